// Round 4
// baseline (420.081 us; speedup 1.0000x reference)
//
#include <hip/hip_runtime.h>

#define N_TOK  1024
#define D_DIM  1024
#define M_FFN  4096

__device__ __forceinline__ float wave_reduce(float v) {
    #pragma unroll
    for (int off = 32; off > 0; off >>= 1) v += __shfl_xor(v, off);
    return v;
}

// ---------------- LayerNorm over 1024-elem rows, f32 -> f32 ---------------
__global__ void ln_kernel(const float* __restrict__ X,
                          const float* __restrict__ gam,
                          const float* __restrict__ bet,
                          float* __restrict__ Y) {
    int b = blockIdx.x, t = threadIdx.x;           // 256 threads, 4 elems each
    float4 x = ((const float4*)(X + (size_t)b * N_TOK))[t];
    float s = x.x + x.y + x.z + x.w;
    float q = x.x*x.x + x.y*x.y + x.z*x.z + x.w*x.w;
    s = wave_reduce(s); q = wave_reduce(q);
    __shared__ float sa[4], sb[4];
    int wid = t >> 6;
    if ((t & 63) == 0) { sa[wid] = s; sb[wid] = q; }
    __syncthreads();
    float ts = sa[0] + sa[1] + sa[2] + sa[3];
    float tq = sb[0] + sb[1] + sb[2] + sb[3];
    float mean = ts * (1.f / N_TOK);
    float var  = tq * (1.f / N_TOK) - mean * mean;
    float rs = rsqrtf(var + 1e-5f);
    float4 g4 = ((const float4*)gam)[t];
    float4 b4 = ((const float4*)bet)[t];
    float4 o;
    o.x = (x.x - mean) * rs * g4.x + b4.x;
    o.y = (x.y - mean) * rs * g4.y + b4.y;
    o.z = (x.z - mean) * rs * g4.z + b4.z;
    o.w = (x.w - mean) * rs * g4.w + b4.w;
    ((float4*)(Y + (size_t)b * N_TOK))[t] = o;
}

// ---- C(32 x N) = A(32 x K) @ W(N x K)^T, lanes span K (coalesced W) ------
// Block 256 thr = 4 waves. lane: ksub = lane&15, nsub = lane>>4.
// Wave = 4 n-cols x 16 m-rows (mhalf = wid&1); block covers 8 n x 32 m.
// Grid: (N/8, ksplit, nmat). 4-step butterfly reduce over ksub; ksub==0
// lanes hold C[m][n]. mode 0: store; 1: silu(v+bias[n]) store; 2: atomicAdd.
__global__ void gemm_kernel(const float* __restrict__ A,
                            const float* __restrict__ W0,
                            const float* __restrict__ W1,
                            float* __restrict__ C0,
                            float* __restrict__ C1,
                            const float* __restrict__ bias,
                            int N, int K, int kchunk, int mode) {
    int t = threadIdx.x;
    int lane = t & 63, wid = t >> 6;
    int ksub = lane & 15, nsub = lane >> 4;
    int mhalf = wid & 1, ngrp = wid >> 1;
    int n = blockIdx.x * 8 + ngrp * 4 + nsub;
    int k0 = blockIdx.y * kchunk + ksub * 4;
    const float* W = blockIdx.z ? W1 : W0;
    float*       C = blockIdx.z ? C1 : C0;
    const float* wp = W + (size_t)n * K + k0;
    const float* ap = A + (size_t)mhalf * 16 * K + k0;
    float acc[16];
    #pragma unroll
    for (int j = 0; j < 16; j++) acc[j] = 0.f;
    for (int kk = 0; kk < kchunk; kk += 64) {
        float4 w4 = *(const float4*)(wp + kk);
        #pragma unroll
        for (int j = 0; j < 16; j++) {
            float4 a4 = *(const float4*)(ap + (size_t)j * K + kk);
            acc[j] += a4.x*w4.x + a4.y*w4.y + a4.z*w4.z + a4.w*w4.w;
        }
    }
    #pragma unroll
    for (int j = 0; j < 16; j++) {
        #pragma unroll
        for (int off = 1; off < 16; off <<= 1)
            acc[j] += __shfl_xor(acc[j], off);
    }
    if (ksub == 0) {
        int mbase = mhalf * 16;
        if (mode == 2) {
            #pragma unroll
            for (int j = 0; j < 16; j++)
                atomicAdd(C + (size_t)(mbase + j) * N + n, acc[j]);
        } else if (mode == 1) {
            float bn = bias[n];
            #pragma unroll
            for (int j = 0; j < 16; j++) {
                float z = acc[j] + bn;
                C[(size_t)(mbase + j) * N + n] = z / (1.f + __expf(-z));
            }
        } else {
            #pragma unroll
            for (int j = 0; j < 16; j++)
                C[(size_t)(mbase + j) * N + n] = acc[j];
        }
    }
}

// ------------- Gaussian-kernel attention row sweep (the big one) ----------
// Persistent waves: one wave processes 4 rows with explicit double-buffer
// prefetch of next row's K/V while computing the current row.
__global__ void attn_kernel(const float* __restrict__ Kp,
                            const float* __restrict__ Vp,
                            const float* __restrict__ Qp,
                            const float* __restrict__ mu_acc,
                            const float* __restrict__ sg_acc,
                            const float* __restrict__ mu_b,
                            const float* __restrict__ sg_b,
                            float* __restrict__ xo) {
    int t = threadIdx.x;
    int lane = t & 63, wid = t >> 6;
    int row0 = blockIdx.x * 16 + wid * 4;
    float4 ck[4], cv[4], nk[4], nv[4];
    {
        const float4* kp = (const float4*)(Kp + (size_t)row0 * D_DIM);
        const float4* vp = (const float4*)(Vp + (size_t)row0 * D_DIM);
        #pragma unroll
        for (int c = 0; c < 4; c++) { ck[c] = kp[c * 64 + lane]; cv[c] = vp[c * 64 + lane]; }
    }
    #pragma unroll
    for (int r = 0; r < 4; r++) {
        int row = row0 + r;
        if (r < 3) {
            const float4* kp = (const float4*)(Kp + (size_t)(row + 1) * D_DIM);
            const float4* vp = (const float4*)(Vp + (size_t)(row + 1) * D_DIM);
            #pragma unroll
            for (int c = 0; c < 4; c++) { nk[c] = kp[c * 64 + lane]; nv[c] = vp[c * 64 + lane]; }
        }
        int i = row & (N_TOK - 1);
        float mu = tanhf(mu_acc[row] + mu_b[i]);
        float sg = sg_acc[row] + sg_b[i];
        float coef = -0.5f / (sg * sg + 1e-8f);
        float acc = 0.f;
        #pragma unroll
        for (int c = 0; c < 4; c++) {
            float d;
            d = ck[c].x - mu; acc += __expf(coef * d * d) * cv[c].x;
            d = ck[c].y - mu; acc += __expf(coef * d * d) * cv[c].y;
            d = ck[c].z - mu; acc += __expf(coef * d * d) * cv[c].z;
            d = ck[c].w - mu; acc += __expf(coef * d * d) * cv[c].w;
        }
        acc = wave_reduce(acc);
        if (lane == 0) xo[row] = acc + Qp[row];
        if (r < 3) {
            #pragma unroll
            for (int c = 0; c < 4; c++) { ck[c] = nk[c]; cv[c] = nv[c]; }
        }
    }
}

// --------------------- out = x + acc2 + b2, f32 ---------------------------
__global__ void final_kernel(const float* __restrict__ x,
                             const float* __restrict__ acc2,
                             const float* __restrict__ b2,
                             float* __restrict__ out) {
    int idx = blockIdx.x * 256 + threadIdx.x;    // 32768 total
    out[idx] = x[idx] + acc2[idx] + b2[idx & (N_TOK - 1)];
}

extern "C" void kernel_launch(void* const* d_in, const int* in_sizes, int n_in,
                              void* d_out, int out_size, void* d_ws, size_t ws_size,
                              hipStream_t stream) {
    const float* Q       = (const float*)d_in[0];
    const float* Kp      = (const float*)d_in[1];
    const float* Vp      = (const float*)d_in[2];
    const float* mu_w    = (const float*)d_in[3];
    const float* mu_b    = (const float*)d_in[4];
    const float* sigma_w = (const float*)d_in[5];
    const float* sigma_b = (const float*)d_in[6];
    const float* w1      = (const float*)d_in[7];
    const float* b1      = (const float*)d_in[8];
    const float* w2      = (const float*)d_in[9];
    const float* b2      = (const float*)d_in[10];
    const float* ln_ff_g = (const float*)d_in[11];
    const float* ln_ff_b = (const float*)d_in[12];
    const float* ln_q_g  = (const float*)d_in[13];
    const float* ln_q_b  = (const float*)d_in[14];

    // Workspace layout (all fp32), ~1.3 MB total
    float* mu_acc = (float*)d_ws;                  // 32768
    float* sg_acc = mu_acc + 32768;                // 32768
    float* f2_acc = sg_acc + 32768;                // 32768 (atomic accum)
    float* xbuf   = f2_acc + 32768;                // 32768
    float* qln    = xbuf   + 32768;                // 32768
    float* h0     = qln    + 32768;                // 32768
    float* g      = h0     + 32768;                // 131072

    // zero only the split-K accumulator for ffn2
    hipMemsetAsync(f2_acc, 0, (size_t)32768 * sizeof(float), stream);

    // 1) q = LN(Q)
    ln_kernel<<<32, 256, 0, stream>>>(Q, ln_q_g, ln_q_b, qln);

    // 2) mu_acc = q @ mu_w^T ; sg_acc = q @ sigma_w^T (one launch, z=matrix)
    gemm_kernel<<<dim3(128, 1, 2), 256, 0, stream>>>(
        qln, mu_w, sigma_w, mu_acc, sg_acc, nullptr, 1024, 1024, 1024, 0);

    // 3) x = sum_d exp(-0.5(K-mu)^2/(sigma^2+1e-8)) * V + Q
    attn_kernel<<<2048, 256, 0, stream>>>(Kp, Vp, Q, mu_acc, sg_acc,
                                          mu_b, sigma_b, xbuf);

    // 4) h0 = LN(x)
    ln_kernel<<<32, 256, 0, stream>>>(xbuf, ln_ff_g, ln_ff_b, h0);

    // 5) g = silu(h0 @ w1^T + b1)   (bias+silu fused in epilogue)
    gemm_kernel<<<dim3(512, 1, 1), 256, 0, stream>>>(
        h0, w1, w1, g, g, b1, 4096, 1024, 1024, 1);

    // 6) f2_acc = g @ w2^T  (split-K x2, atomics) ; out = x + f2_acc + b2
    gemm_kernel<<<dim3(128, 2, 1), 256, 0, stream>>>(
        g, w2, w2, f2_acc, f2_acc, nullptr, 1024, 4096, 2048, 2);
    final_kernel<<<128, 256, 0, stream>>>(xbuf, f2_acc, b2, (float*)d_out);
}

// Round 5
// 398.417 us; speedup vs baseline: 1.0544x; 1.0544x over previous
//
#include <hip/hip_runtime.h>

#define N_TOK  1024
#define D_DIM  1024
#define M_FFN  4096

typedef float f32x4 __attribute__((ext_vector_type(4)));

__device__ __forceinline__ float wave_reduce(float v) {
    #pragma unroll
    for (int off = 32; off > 0; off >>= 1) v += __shfl_xor(v, off);
    return v;
}

// ---------------- LayerNorm over 1024-elem rows, f32 -> f32 ---------------
__global__ void ln_kernel(const float* __restrict__ X,
                          const float* __restrict__ gam,
                          const float* __restrict__ bet,
                          float* __restrict__ Y) {
    int b = blockIdx.x, t = threadIdx.x;           // 256 threads, 4 elems each
    float4 x = ((const float4*)(X + (size_t)b * N_TOK))[t];
    float s = x.x + x.y + x.z + x.w;
    float q = x.x*x.x + x.y*x.y + x.z*x.z + x.w*x.w;
    s = wave_reduce(s); q = wave_reduce(q);
    __shared__ float sa[4], sb[4];
    int wid = t >> 6;
    if ((t & 63) == 0) { sa[wid] = s; sb[wid] = q; }
    __syncthreads();
    float ts = sa[0] + sa[1] + sa[2] + sa[3];
    float tq = sb[0] + sb[1] + sb[2] + sb[3];
    float mean = ts * (1.f / N_TOK);
    float var  = tq * (1.f / N_TOK) - mean * mean;
    float rs = rsqrtf(var + 1e-5f);
    float4 g4 = ((const float4*)gam)[t];
    float4 b4 = ((const float4*)bet)[t];
    float4 o;
    o.x = (x.x - mean) * rs * g4.x + b4.x;
    o.y = (x.y - mean) * rs * g4.y + b4.y;
    o.z = (x.z - mean) * rs * g4.z + b4.z;
    o.w = (x.w - mean) * rs * g4.w + b4.w;
    ((float4*)(Y + (size_t)b * N_TOK))[t] = o;
}

// ---- C(32 x N) = A(32 x K) @ W(N x K)^T, lanes span K (coalesced W) ------
// Shared body; each call site gets a distinctly-NAMED kernel so rocprof
// attributes time per GEMM. W loads are nontemporal (streamed once).
__device__ __forceinline__ void gemm_body(const float* __restrict__ A,
                                          const float* __restrict__ W,
                                          float* __restrict__ C,
                                          const float* __restrict__ bias,
                                          int N, int K, int kchunk, int mode,
                                          int bx, int by) {
    int t = threadIdx.x;
    int lane = t & 63, wid = t >> 6;
    int ksub = lane & 15, nsub = lane >> 4;
    int mhalf = wid & 1, ngrp = wid >> 1;
    int n = bx * 8 + ngrp * 4 + nsub;
    int k0 = by * kchunk + ksub * 4;
    const float* wp = W + (size_t)n * K + k0;
    const float* ap = A + (size_t)mhalf * 16 * K + k0;
    float acc[16];
    #pragma unroll
    for (int j = 0; j < 16; j++) acc[j] = 0.f;
    for (int kk = 0; kk < kchunk; kk += 64) {
        f32x4 w4 = __builtin_nontemporal_load((const f32x4*)(wp + kk));
        #pragma unroll
        for (int j = 0; j < 16; j++) {
            float4 a4 = *(const float4*)(ap + (size_t)j * K + kk);
            acc[j] += a4.x*w4.x + a4.y*w4.y + a4.z*w4.z + a4.w*w4.w;
        }
    }
    #pragma unroll
    for (int j = 0; j < 16; j++) {
        #pragma unroll
        for (int off = 1; off < 16; off <<= 1)
            acc[j] += __shfl_xor(acc[j], off);
    }
    if (ksub == 0) {
        int mbase = mhalf * 16;
        if (mode == 2) {
            #pragma unroll
            for (int j = 0; j < 16; j++)
                atomicAdd(C + (size_t)(mbase + j) * N + n, acc[j]);
        } else if (mode == 1) {
            float bn = bias[n];
            #pragma unroll
            for (int j = 0; j < 16; j++) {
                float z = acc[j] + bn;
                C[(size_t)(mbase + j) * N + n] = z / (1.f + __expf(-z));
            }
        } else {
            #pragma unroll
            for (int j = 0; j < 16; j++)
                C[(size_t)(mbase + j) * N + n] = acc[j];
        }
    }
}

// mu/sigma GEMM: grid (128, 1, 2); z selects weight/output pair
__global__ void gemm_mu_sigma(const float* __restrict__ A,
                              const float* __restrict__ W0,
                              const float* __restrict__ W1,
                              float* __restrict__ C0,
                              float* __restrict__ C1) {
    const float* W = blockIdx.z ? W1 : W0;
    float*       C = blockIdx.z ? C1 : C0;
    gemm_body(A, W, C, nullptr, 1024, 1024, 1024, 0, blockIdx.x, 0);
}

// ffn1 GEMM: grid (512); fused bias+silu epilogue
__global__ void gemm_ffn1(const float* __restrict__ A,
                          const float* __restrict__ W,
                          float* __restrict__ C,
                          const float* __restrict__ bias) {
    gemm_body(A, W, C, bias, 4096, 1024, 1024, 1, blockIdx.x, 0);
}

// ffn2 GEMM: grid (128, 2); split-K atomics into zeroed accumulator
__global__ void gemm_ffn2(const float* __restrict__ A,
                          const float* __restrict__ W,
                          float* __restrict__ C) {
    gemm_body(A, W, C, nullptr, 1024, 4096, 2048, 2, blockIdx.x, blockIdx.y);
}

// ------------- Gaussian-kernel attention row sweep (the big one) ----------
// Two rows per 256-thread block; nontemporal float4 loads (streamed data,
// bypass/evict-first L1 so 4KB-strided concurrent rows don't alias-thrash).
__global__ void attn_kernel(const float* __restrict__ Kp,
                            const float* __restrict__ Vp,
                            const float* __restrict__ Qp,
                            const float* __restrict__ mu_acc,
                            const float* __restrict__ sg_acc,
                            const float* __restrict__ mu_b,
                            const float* __restrict__ sg_b,
                            float* __restrict__ xo) {
    int t = threadIdx.x;
    int rowa = blockIdx.x * 2;
    int rowb = rowa + 1;
    const f32x4* kp = (const f32x4*)(Kp + (size_t)rowa * D_DIM);
    const f32x4* vp = (const f32x4*)(Vp + (size_t)rowa * D_DIM);
    f32x4 kA = __builtin_nontemporal_load(kp + t);
    f32x4 kB = __builtin_nontemporal_load(kp + 256 + t);
    f32x4 vA = __builtin_nontemporal_load(vp + t);
    f32x4 vB = __builtin_nontemporal_load(vp + 256 + t);
    int ia = rowa & (N_TOK - 1), ib = rowb & (N_TOK - 1);
    float muA = tanhf(mu_acc[rowa] + mu_b[ia]);
    float muB = tanhf(mu_acc[rowb] + mu_b[ib]);
    float sgA = sg_acc[rowa] + sg_b[ia];
    float sgB = sg_acc[rowb] + sg_b[ib];
    float cA = -0.5f / (sgA * sgA + 1e-8f);
    float cB = -0.5f / (sgB * sgB + 1e-8f);
    float accA = 0.f, accB = 0.f, d;
    d = kA.x - muA; accA += __expf(cA * d * d) * vA.x;
    d = kA.y - muA; accA += __expf(cA * d * d) * vA.y;
    d = kA.z - muA; accA += __expf(cA * d * d) * vA.z;
    d = kA.w - muA; accA += __expf(cA * d * d) * vA.w;
    d = kB.x - muB; accB += __expf(cB * d * d) * vB.x;
    d = kB.y - muB; accB += __expf(cB * d * d) * vB.y;
    d = kB.z - muB; accB += __expf(cB * d * d) * vB.z;
    d = kB.w - muB; accB += __expf(cB * d * d) * vB.w;
    accA = wave_reduce(accA); accB = wave_reduce(accB);
    __shared__ float sA[4], sB[4];
    int wid = t >> 6;
    if ((t & 63) == 0) { sA[wid] = accA; sB[wid] = accB; }
    __syncthreads();
    if (t == 0)  xo[rowa] = sA[0] + sA[1] + sA[2] + sA[3] + Qp[rowa];
    if (t == 64) xo[rowb] = sB[0] + sB[1] + sB[2] + sB[3] + Qp[rowb];
}

// --------------------- out = x + acc2 + b2, f32 ---------------------------
__global__ void final_kernel(const float* __restrict__ x,
                             const float* __restrict__ acc2,
                             const float* __restrict__ b2,
                             float* __restrict__ out) {
    int idx = blockIdx.x * 256 + threadIdx.x;    // 32768 total
    out[idx] = x[idx] + acc2[idx] + b2[idx & (N_TOK - 1)];
}

extern "C" void kernel_launch(void* const* d_in, const int* in_sizes, int n_in,
                              void* d_out, int out_size, void* d_ws, size_t ws_size,
                              hipStream_t stream) {
    const float* Q       = (const float*)d_in[0];
    const float* Kp      = (const float*)d_in[1];
    const float* Vp      = (const float*)d_in[2];
    const float* mu_w    = (const float*)d_in[3];
    const float* mu_b    = (const float*)d_in[4];
    const float* sigma_w = (const float*)d_in[5];
    const float* sigma_b = (const float*)d_in[6];
    const float* w1      = (const float*)d_in[7];
    const float* b1      = (const float*)d_in[8];
    const float* w2      = (const float*)d_in[9];
    const float* b2      = (const float*)d_in[10];
    const float* ln_ff_g = (const float*)d_in[11];
    const float* ln_ff_b = (const float*)d_in[12];
    const float* ln_q_g  = (const float*)d_in[13];
    const float* ln_q_b  = (const float*)d_in[14];

    // Workspace layout (all fp32), ~1.3 MB total
    float* mu_acc = (float*)d_ws;                  // 32768
    float* sg_acc = mu_acc + 32768;                // 32768
    float* f2_acc = sg_acc + 32768;                // 32768 (atomic accum)
    float* xbuf   = f2_acc + 32768;                // 32768
    float* qln    = xbuf   + 32768;                // 32768
    float* h0     = qln    + 32768;                // 32768
    float* g      = h0     + 32768;                // 131072

    // zero only the split-K accumulator for ffn2
    hipMemsetAsync(f2_acc, 0, (size_t)32768 * sizeof(float), stream);

    // 1) q = LN(Q)
    ln_kernel<<<32, 256, 0, stream>>>(Q, ln_q_g, ln_q_b, qln);

    // 2) mu_acc = q @ mu_w^T ; sg_acc = q @ sigma_w^T
    gemm_mu_sigma<<<dim3(128, 1, 2), 256, 0, stream>>>(
        qln, mu_w, sigma_w, mu_acc, sg_acc);

    // 3) x = sum_d exp(-0.5(K-mu)^2/(sigma^2+1e-8)) * V + Q
    attn_kernel<<<16384, 256, 0, stream>>>(Kp, Vp, Q, mu_acc, sg_acc,
                                           mu_b, sigma_b, xbuf);

    // 4) h0 = LN(x)
    ln_kernel<<<32, 256, 0, stream>>>(xbuf, ln_ff_g, ln_ff_b, h0);

    // 5) g = silu(h0 @ w1^T + b1)   (bias+silu fused in epilogue)
    gemm_ffn1<<<512, 256, 0, stream>>>(h0, w1, g, b1);

    // 6) f2_acc = g @ w2^T  (split-K x2, atomics) ; out = x + f2_acc + b2
    gemm_ffn2<<<dim3(128, 2), 256, 0, stream>>>(g, w2, f2_acc);
    final_kernel<<<128, 256, 0, stream>>>(xbuf, f2_acc, b2, (float*)d_out);
}